// Round 5
// baseline (1103.969 us; speedup 1.0000x reference)
//
#include <hip/hip_runtime.h>
#include <math.h>

// ---------------------------------------------------------------------------
// TannerGNN. Round 5: k_gru re-blocked — 16 nodes/thread (96 accumulators),
// coalesced L2-hot weight stream, wave-uniform LDS broadcasts. fp32 math
// order identical to R4 (absmax must not move). k_msg unchanged from R4.
// N_NODES=50000, N_EDGES=400000, H=128, L=3, T=2, FEAT=4, N_DATA=40000.
// ---------------------------------------------------------------------------

#define H 128
#define TE2 128        // edges per message block (8 waves x 16)
#define MS2 129        // sMsg row stride in f32
#define HS  136        // sHid row stride in bf16 (within wave strip)
#define FEAT 4

typedef __bf16 bf16x8 __attribute__((ext_vector_type(8)));
typedef float  f32x4  __attribute__((ext_vector_type(4)));

// ---------------- input projection: h = relu(x @ W_in + b_in) --------------
__global__ __launch_bounds__(256) void k_input(
    const float* __restrict__ x, const float* __restrict__ Win,
    const float* __restrict__ bin, float* __restrict__ h,
    __bf16* __restrict__ hb, int n_nodes)
{
    int idx = blockIdx.x * 256 + threadIdx.x;
    if (idx >= n_nodes * H) return;
    int n = idx >> 7, j = idx & 127;
    float acc = bin[j];
#pragma unroll
    for (int f = 0; f < FEAT; f++)
        acc += x[n * FEAT + f] * Win[f * H + j];
    float v = fmaxf(acc, 0.f);
    h[idx] = v;
    hb[idx] = (__bf16)v;
}

// ---------------- weight conversion: bf16, MFMA-fragment order -------------
__global__ __launch_bounds__(256) void k_wconv(
    const float* __restrict__ W1, const float* __restrict__ W2,
    __bf16* __restrict__ Wsw)
{
    int gid = blockIdx.x * 256 + threadIdx.x;
    const int per_lt = 12 * 4096;
    if (gid >= 6 * per_lt) return;
    int lt = gid / per_lt, rem = gid % per_lt;
    int chunk = rem >> 12;
    int within = rem & 4095;
    int ct = within >> 9;
    int lane = (within >> 3) & 63;
    int j = within & 7;
    int r = lane & 15, quad = lane >> 4;
    int n = ct * 16 + r;
    float v;
    if (chunk < 8) {
        int k = chunk * 32 + quad * 8 + j;
        v = W1[((size_t)lt * 256 + k) * 128 + n];
    } else {
        int k = (chunk - 8) * 32 + quad * 8 + j;
        v = W2[((size_t)lt * 128 + k) * 128 + n];
    }
    Wsw[gid] = (__bf16)v;
}

// ---------------- counting sort by key = type*nn + dst ---------------------
__global__ __launch_bounds__(256) void k_hist(
    const int* __restrict__ et, const int* __restrict__ dst,
    int* __restrict__ cnt, int n_edges, int nn)
{
    int i = blockIdx.x * 256 + threadIdx.x;
    if (i < n_edges) atomicAdd(&cnt[et[i] * nn + dst[i]], 1);
}

__global__ __launch_bounds__(1024) void k_scan(
    const int* __restrict__ cnt, int* __restrict__ offs, int n)
{
    __shared__ int sW[16];
    __shared__ int sBase;
    if (threadIdx.x == 0) sBase = 0;
    __syncthreads();
    int lane = threadIdx.x & 63, w = threadIdx.x >> 6;
    for (int c = 0; c < n; c += 1024) {
        int idx = c + threadIdx.x;
        int v = (idx < n) ? cnt[idx] : 0;
        int orig = v;
#pragma unroll
        for (int off = 1; off < 64; off <<= 1) {
            int t = __shfl_up(v, off, 64);
            if (lane >= off) v += t;
        }
        if (lane == 63) sW[w] = v;
        __syncthreads();
        if (w == 0 && lane < 16) {
            int x = sW[lane];
#pragma unroll
            for (int off = 1; off < 16; off <<= 1) {
                int t = __shfl_up(x, off, 64);
                if (lane >= off) x += t;
            }
            sW[lane] = x;
        }
        __syncthreads();
        int wbase = w ? sW[w - 1] : 0;
        int base = sBase;
        if (idx < n) offs[idx] = base + wbase + v - orig;
        __syncthreads();
        if (threadIdx.x == 0) sBase = base + sW[15];
        __syncthreads();
    }
    if (threadIdx.x == 0) offs[n] = sBase;
}

__global__ __launch_bounds__(256) void k_place(
    const int* __restrict__ et, const int* __restrict__ dst,
    const int* __restrict__ offs, int* __restrict__ cur,
    int* __restrict__ bucket, int n_edges, int nn)
{
    int i = blockIdx.x * 256 + threadIdx.x;
    if (i < n_edges) {
        int key = et[i] * nn + dst[i];
        int p = atomicAdd(&cur[key], 1);
        bucket[offs[key] + p] = i;
    }
}

// ---------------- fused MFMA message kernel (unchanged from R4) ------------
__global__ __launch_bounds__(512, 4) void k_msg(
    const __bf16* __restrict__ hb,
    const int* __restrict__ bucket, const int* __restrict__ offs,
    const int* __restrict__ src, const int* __restrict__ dst,
    const __bf16* __restrict__ Wsw, const float* __restrict__ b1l,
    const float* __restrict__ b2l,
    float* __restrict__ agg, int n_edges, int nn)
{
    const int t = blockIdx.y;
    const int c0 = offs[nn];
    const int cnt = t ? (n_edges - c0) : c0;
    const int base = t ? c0 : 0;
    const int start = blockIdx.x * TE2;
    if (start >= cnt) return;

    const __bf16* __restrict__ W = Wsw + (size_t)t * 12 * 4096;
    const float*  __restrict__ b1 = b1l + t * H;
    const float*  __restrict__ b2 = b2l + t * H;

    __shared__ __bf16 sW[4096];            // 8 KB weight chunk
    __shared__ float  sMsg[TE2 * MS2];     // 66048 B; sHid aliases per-wave
    __shared__ int    sDstV[TE2];

    const int tid  = threadIdx.x;
    const int lane = tid & 63;
    const int w    = tid >> 6;
    const int r    = lane & 15;
    const int quad = lane >> 4;

    f32x4 wreg[12];
#pragma unroll
    for (int c = 0; c < 12; c++)
        wreg[c] = *(const f32x4*)(W + c * 4096 + tid * 8);

    if (tid < TE2) {
        int i = start + tid;
        sDstV[tid] = (i < cnt) ? dst[bucket[base + i]] : -1;
    }

    int ei = start + w * 16 + r;
    int e = bucket[base + (ei < cnt ? ei : cnt - 1)];
    const __bf16* aps = hb + (size_t)src[e] * H;
    const __bf16* apd = hb + (size_t)dst[e] * H;

    bf16x8 afS[4];
#pragma unroll
    for (int i = 0; i < 4; i++)
        afS[i] = *(const bf16x8*)(aps + i * 32 + quad * 8);

    __syncthreads();

    f32x4 acc[8];
#pragma unroll
    for (int ct = 0; ct < 8; ct++) acc[ct] = (f32x4){0.f, 0.f, 0.f, 0.f};

    bf16x8 afD[4];
#pragma unroll
    for (int kc = 0; kc < 8; kc++) {
        __syncthreads();
        *(f32x4*)(sW + tid * 8) = wreg[kc];
        __syncthreads();
        if (kc == 2) {
#pragma unroll
            for (int i = 0; i < 4; i++)
                afD[i] = *(const bf16x8*)(apd + i * 32 + quad * 8);
        }
        bf16x8 a = (kc < 4) ? afS[kc] : afD[kc - 4];
#pragma unroll
        for (int ct = 0; ct < 8; ct++) {
            bf16x8 b = *(const bf16x8*)(sW + ct * 512 + lane * 8);
            acc[ct] = __builtin_amdgcn_mfma_f32_16x16x32_bf16(a, b, acc[ct], 0, 0, 0);
        }
    }

    __bf16* sHid = (__bf16*)(sMsg + w * 16 * MS2);
#pragma unroll
    for (int ct = 0; ct < 8; ct++) {
        int col = ct * 16 + r;
        float bb = b1[col];
#pragma unroll
        for (int g = 0; g < 4; g++) {
            float v = fmaxf(acc[ct][g] + bb, 0.f);
            sHid[(quad * 4 + g) * HS + col] = (__bf16)v;
        }
    }

    f32x4 acc2[8];
#pragma unroll
    for (int ct = 0; ct < 8; ct++) acc2[ct] = (f32x4){0.f, 0.f, 0.f, 0.f};
#pragma unroll
    for (int kc = 0; kc < 4; kc++) {
        __syncthreads();
        *(f32x4*)(sW + tid * 8) = wreg[8 + kc];
        __syncthreads();
        bf16x8 a = *(const bf16x8*)(sHid + r * HS + kc * 32 + quad * 8);
#pragma unroll
        for (int ct = 0; ct < 8; ct++) {
            bf16x8 b = *(const bf16x8*)(sW + ct * 512 + lane * 8);
            acc2[ct] = __builtin_amdgcn_mfma_f32_16x16x32_bf16(a, b, acc2[ct], 0, 0, 0);
        }
    }

#pragma unroll
    for (int ct = 0; ct < 8; ct++) {
        int col = ct * 16 + r;
        float bb = b2[col];
#pragma unroll
        for (int g = 0; g < 4; g++)
            sMsg[(w * 16 + quad * 4 + g) * MS2 + col] = acc2[ct][g] + bb;
    }
    __syncthreads();

    {
        int j = tid & 127, strip = tid >> 7;
        int e0 = strip * 32;
        float run = 0.f; int curd = -1;
        for (int q = 0; q < 32; q++) {
            int d = sDstV[e0 + q];
            float v = sMsg[(e0 + q) * MS2 + j];
            if (d != curd) {
                if (curd >= 0) atomicAdd(agg + (size_t)curd * H + j, run);
                run = 0.f; curd = d;
            }
            if (d >= 0) run += v;
        }
        if (curd >= 0) atomicAdd(agg + (size_t)curd * H + j, run);
    }
}

// ---------------- GRU cell (32 nodes/block, 16 nodes/thread) ---------------
// Thread (j = tid&127, g = tid>>7) accumulates 6 gate streams for 16 nodes:
// 96 FMAs per k against 6 coalesced weight loads + 32 wave-uniform LDS
// broadcasts. fp32, accumulation order identical to R4.
__global__ __launch_bounds__(256, 3) void k_gru(
    float* __restrict__ h, __bf16* __restrict__ hb,
    const float* __restrict__ agg,
    const float* __restrict__ Wih, const float* __restrict__ bih,
    const float* __restrict__ Whh, const float* __restrict__ bhh,
    int n_nodes)
{
    const int nb = blockIdx.x * 32;
    const int tid = threadIdx.x;

    __shared__ float sA[32][H], sH[32][H];   // 32 KB
#pragma unroll
    for (int v = 0; v < 4; v++) {
        int f = tid + 256 * v;               // float4 index
        int e = f >> 5, c4 = (f & 31) * 4;
        int n = nb + e;
        if (n < n_nodes) {
            *(float4*)&sA[e][c4] = *(const float4*)(agg + (size_t)n * H + c4);
            *(float4*)&sH[e][c4] = *(const float4*)(h   + (size_t)n * H + c4);
        }
    }
    __syncthreads();

    const int j = tid & 127;
    const int g = tid >> 7;           // 0/1

    float ar[16], az[16], an[16], gr[16], gz[16], gn[16];
#pragma unroll
    for (int i = 0; i < 16; i++) {
        ar[i] = 0.f; az[i] = 0.f; an[i] = 0.f;
        gr[i] = 0.f; gz[i] = 0.f; gn[i] = 0.f;
    }

    const float* __restrict__ wp = Wih + j;
    const float* __restrict__ vp = Whh + j;
    for (int k = 0; k < H; k++) {
        float wr = wp[k * 384];
        float wz = wp[k * 384 + 128];
        float wn = wp[k * 384 + 256];
        float vr = vp[k * 384];
        float vz = vp[k * 384 + 128];
        float vn = vp[k * 384 + 256];
#pragma unroll
        for (int i = 0; i < 16; i++) {
            int e = g + 2 * i;
            float a = sA[e][k], hh = sH[e][k];
            ar[i] += a * wr;  az[i] += a * wz;  an[i] += a * wn;
            gr[i] += hh * vr; gz[i] += hh * vz; gn[i] += hh * vn;
        }
    }

    float br_ = bih[j], bz_ = bih[128 + j], bn_ = bih[256 + j];
    float cr = bhh[j], cz = bhh[128 + j], cn = bhh[256 + j];
#pragma unroll
    for (int i = 0; i < 16; i++) {
        int e = g + 2 * i;
        int n = nb + e;
        if (n < n_nodes) {
            float rr = 1.f / (1.f + expf(-(ar[i] + br_ + gr[i] + cr)));
            float zz = 1.f / (1.f + expf(-(az[i] + bz_ + gz[i] + cz)));
            float nv = tanhf(an[i] + bn_ + rr * (gn[i] + cn));
            float out = (1.f - zz) * nv + zz * sH[e][j];
            h[(size_t)n * H + j] = out;
            hb[(size_t)n * H + j] = (__bf16)out;
        }
    }
}

// ---------------- readout: out = relu(h@Wr1+br1) @ Wr2 + br2 ---------------
__global__ __launch_bounds__(128) void k_readout(
    const float* __restrict__ h, const float* __restrict__ Wr1,
    const float* __restrict__ br1, const float* __restrict__ Wr2,
    const float* __restrict__ br2, float* __restrict__ out, int n_out)
{
    const int n0 = blockIdx.x * 8;
    const int tid = threadIdx.x;     // 128
    __shared__ float sh[8][H];
    __shared__ float sRed[2][8];
    {
        int e = tid >> 4, q = (tid & 15) * 8;
        int n = n0 + e;
        if (n < n_out) {
            const float* hp = h + (size_t)n * H + q;
            *(float4*)&sh[e][q]     = *(const float4*)hp;
            *(float4*)&sh[e][q + 4] = *(const float4*)(hp + 4);
        }
    }
    __syncthreads();

    const int j = tid;
    float bb = br1[j];
    float acc[8];
#pragma unroll
    for (int e = 0; e < 8; e++) acc[e] = bb;
    for (int k = 0; k < H; k++) {
        float wv = Wr1[k * H + j];
#pragma unroll
        for (int e = 0; e < 8; e++) acc[e] += sh[e][k] * wv;
    }
    float w2 = Wr2[j];
    int lane = tid & 63, w = tid >> 6;
#pragma unroll
    for (int e = 0; e < 8; e++) {
        float val = fmaxf(acc[e], 0.f) * w2;
#pragma unroll
        for (int off = 32; off > 0; off >>= 1)
            val += __shfl_down(val, off, 64);
        if (lane == 0) sRed[w][e] = val;
    }
    __syncthreads();
    if (tid < 8 && n0 + tid < n_out)
        out[n0 + tid] = sRed[0][tid] + sRed[1][tid] + br2[0];
}

// ---------------------------------------------------------------------------
extern "C" void kernel_launch(void* const* d_in, const int* in_sizes, int n_in,
                              void* d_out, int out_size, void* d_ws, size_t ws_size,
                              hipStream_t stream)
{
    const float* x      = (const float*)d_in[0];
    const int*   eidx   = (const int*)d_in[1];
    const int*   etype  = (const int*)d_in[2];
    const float* Win    = (const float*)d_in[4];
    const float* bin    = (const float*)d_in[5];
    const float* W1     = (const float*)d_in[6];   // (3,2,256,128)
    const float* b1     = (const float*)d_in[7];   // (3,2,128)
    const float* W2     = (const float*)d_in[8];   // (3,2,128,128)
    const float* b2     = (const float*)d_in[9];   // (3,2,128)
    const float* Wih    = (const float*)d_in[10];  // (3,128,384)
    const float* bih    = (const float*)d_in[11];  // (3,384)
    const float* Whh    = (const float*)d_in[12];  // (3,128,384)
    const float* bhh    = (const float*)d_in[13];  // (3,384)
    const float* Wr1    = (const float*)d_in[14];
    const float* br1    = (const float*)d_in[15];
    const float* Wr2    = (const float*)d_in[16];
    const float* br2    = (const float*)d_in[17];

    const int n_nodes = in_sizes[0] / FEAT;
    const int n_edges = in_sizes[1] / 2;
    const int L = 3;
    const size_t nh = (size_t)n_nodes * H;

    const int* src = eidx;
    const int* dst = eidx + n_edges;

    // workspace carve-up
    float*  h    = (float*)d_ws;                    // 25.6 MB
    float*  agg  = h + nh;                          // 25.6 MB
    __bf16* hb   = (__bf16*)(agg + nh);             // 12.8 MB
    __bf16* Wsw  = hb + nh;                         // 6*12*4096 bf16
    int* bucket  = (int*)(Wsw + 6 * 12 * 4096);     // n_edges
    int* cnt     = bucket + n_edges;                // 2*nn
    int* cur     = cnt + 2 * n_nodes;               // 2*nn
    int* offs    = cur + 2 * n_nodes;               // 2*nn + 1

    hipMemsetAsync(cnt, 0, (size_t)2 * n_nodes * sizeof(int), stream);
    hipMemsetAsync(cur, 0, (size_t)2 * n_nodes * sizeof(int), stream);

    k_wconv<<<(6 * 12 * 4096 + 255) / 256, 256, 0, stream>>>(W1, W2, Wsw);
    k_input<<<((int)nh + 255) / 256, 256, 0, stream>>>(x, Win, bin, h, hb, n_nodes);

    const int eb = (n_edges + 255) / 256;
    k_hist <<<eb, 256, 0, stream>>>(etype, dst, cnt, n_edges, n_nodes);
    k_scan <<<1, 1024, 0, stream>>>(cnt, offs, 2 * n_nodes);
    k_place<<<eb, 256, 0, stream>>>(etype, dst, offs, cur, bucket, n_edges, n_nodes);

    const dim3 mgrid((n_edges + TE2 - 1) / TE2, 2);
    for (int l = 0; l < L; l++) {
        hipMemsetAsync(agg, 0, nh * sizeof(float), stream);
        k_msg<<<mgrid, 512, 0, stream>>>(
            hb, bucket, offs, src, dst,
            Wsw + (size_t)l * 2 * 12 * 4096,
            b1 + (size_t)l * 2 * H, b2 + (size_t)l * 2 * H,
            agg, n_edges, n_nodes);
        k_gru<<<(n_nodes + 31) / 32, 256, 0, stream>>>(
            h, hb, agg,
            Wih + (size_t)l * H * 384, bih + (size_t)l * 384,
            Whh + (size_t)l * H * 384, bhh + (size_t)l * 384,
            n_nodes);
    }

    k_readout<<<(out_size + 7) / 8, 128, 0, stream>>>(
        h, Wr1, br1, Wr2, br2, (float*)d_out, out_size);
}

// Round 7
// 770.073 us; speedup vs baseline: 1.4336x; 1.4336x over previous
//
#include <hip/hip_runtime.h>
#include <math.h>

// ---------------------------------------------------------------------------
// TannerGNN. Round 7: fix R6's Wg layout constant (per_layer 98304 -> 196608;
// Whh was never written, GRU used garbage recurrent weights). Split-precision
// bf16 MFMA GRU otherwise unchanged. k_msg unchanged from R4.
// N_NODES=50000, N_EDGES=400000, H=128, L=3, T=2, FEAT=4, N_DATA=40000.
// ---------------------------------------------------------------------------

#define H 128
#define TE2 128        // edges per message block (8 waves x 16)
#define MS2 129        // sMsg row stride in f32
#define HS  136        // sHid row stride in bf16 (within wave strip)
#define FEAT 4
#define WG_PER_LAYER 196608   // 2 mat * 2 split * 4 kc * 24 jtg * 64 lane * 8

typedef __bf16 bf16x8 __attribute__((ext_vector_type(8)));
typedef __bf16 bf16x4 __attribute__((ext_vector_type(4)));
typedef float  f32x4  __attribute__((ext_vector_type(4)));

// ---------------- input projection: h = relu(x @ W_in + b_in) --------------
__global__ __launch_bounds__(256) void k_input(
    const float* __restrict__ x, const float* __restrict__ Win,
    const float* __restrict__ bin, float* __restrict__ h,
    __bf16* __restrict__ hb, int n_nodes)
{
    int idx = blockIdx.x * 256 + threadIdx.x;
    if (idx >= n_nodes * H) return;
    int n = idx >> 7, j = idx & 127;
    float acc = bin[j];
#pragma unroll
    for (int f = 0; f < FEAT; f++)
        acc += x[n * FEAT + f] * Win[f * H + j];
    float v = fmaxf(acc, 0.f);
    h[idx] = v;
    hb[idx] = (__bf16)v;
}

// ---------------- message-weight conversion: bf16, MFMA-fragment order -----
__global__ __launch_bounds__(256) void k_wconv(
    const float* __restrict__ W1, const float* __restrict__ W2,
    __bf16* __restrict__ Wsw)
{
    int gid = blockIdx.x * 256 + threadIdx.x;
    const int per_lt = 12 * 4096;
    if (gid >= 6 * per_lt) return;
    int lt = gid / per_lt, rem = gid % per_lt;
    int chunk = rem >> 12;
    int within = rem & 4095;
    int ct = within >> 9;
    int lane = (within >> 3) & 63;
    int j = within & 7;
    int r = lane & 15, quad = lane >> 4;
    int n = ct * 16 + r;
    float v;
    if (chunk < 8) {
        int k = chunk * 32 + quad * 8 + j;
        v = W1[((size_t)lt * 256 + k) * 128 + n];
    } else {
        int k = (chunk - 8) * 32 + quad * 8 + j;
        v = W2[((size_t)lt * 128 + k) * 128 + n];
    }
    Wsw[gid] = (__bf16)v;
}

// ---------------- GRU-weight conversion: hi/lo split, B-fragment order -----
// Per layer WG_PER_LAYER elems: ((((mat*2+split)*4 + kc)*24 + jtg)*64+lane)*8+t
// mat: 0=Wih 1=Whh; split: 0=hi 1=lo; kc: k-chunk of 32; jtg: col-tile (384/16)
// k = kc*32 + (lane>>4)*8 + t ; n = jtg*16 + (lane&15) ; value = W[k*384+n]
__global__ __launch_bounds__(256) void k_wgconv(
    const float* __restrict__ Wih, const float* __restrict__ Whh,
    __bf16* __restrict__ Wg)
{
    int gid = blockIdx.x * 256 + threadIdx.x;
    if (gid >= 3 * WG_PER_LAYER) return;
    int layer = gid / WG_PER_LAYER, rem = gid % WG_PER_LAYER;
    int t = rem & 7;
    int lane = (rem >> 3) & 63;
    int jtg = (rem >> 9) % 24;
    int mk = rem / 12288;          // (mat*2+split)*4 + kc, 0..15
    int kc = mk & 3;
    int msplit = mk >> 2;          // 0..3
    int mat = msplit >> 1, split = msplit & 1;
    int r = lane & 15, quad = lane >> 4;
    int k = kc * 32 + quad * 8 + t;
    int n = jtg * 16 + r;
    const float* W = (mat ? Whh : Wih) + (size_t)layer * 128 * 384;
    float v = W[(size_t)k * 384 + n];
    __bf16 hi = (__bf16)v;
    Wg[gid] = split ? (__bf16)(v - (float)hi) : hi;
}

// ---------------- counting sort by key = type*nn + dst ---------------------
__global__ __launch_bounds__(256) void k_hist(
    const int* __restrict__ et, const int* __restrict__ dst,
    int* __restrict__ cnt, int n_edges, int nn)
{
    int i = blockIdx.x * 256 + threadIdx.x;
    if (i < n_edges) atomicAdd(&cnt[et[i] * nn + dst[i]], 1);
}

__global__ __launch_bounds__(1024) void k_scan(
    const int* __restrict__ cnt, int* __restrict__ offs, int n)
{
    __shared__ int sW[16];
    __shared__ int sBase;
    if (threadIdx.x == 0) sBase = 0;
    __syncthreads();
    int lane = threadIdx.x & 63, w = threadIdx.x >> 6;
    for (int c = 0; c < n; c += 1024) {
        int idx = c + threadIdx.x;
        int v = (idx < n) ? cnt[idx] : 0;
        int orig = v;
#pragma unroll
        for (int off = 1; off < 64; off <<= 1) {
            int t = __shfl_up(v, off, 64);
            if (lane >= off) v += t;
        }
        if (lane == 63) sW[w] = v;
        __syncthreads();
        if (w == 0 && lane < 16) {
            int x = sW[lane];
#pragma unroll
            for (int off = 1; off < 16; off <<= 1) {
                int t = __shfl_up(x, off, 64);
                if (lane >= off) x += t;
            }
            sW[lane] = x;
        }
        __syncthreads();
        int wbase = w ? sW[w - 1] : 0;
        int base = sBase;
        if (idx < n) offs[idx] = base + wbase + v - orig;
        __syncthreads();
        if (threadIdx.x == 0) sBase = base + sW[15];
        __syncthreads();
    }
    if (threadIdx.x == 0) offs[n] = sBase;
}

// claims slots by decrementing cnt (cnt is dead after k_scan; ends all-zero)
__global__ __launch_bounds__(256) void k_place(
    const int* __restrict__ et, const int* __restrict__ dst,
    const int* __restrict__ offs, int* __restrict__ cnt,
    int* __restrict__ bucket, int n_edges, int nn)
{
    int i = blockIdx.x * 256 + threadIdx.x;
    if (i < n_edges) {
        int key = et[i] * nn + dst[i];
        int p = atomicAdd(&cnt[key], -1) - 1;
        bucket[offs[key] + p] = i;
    }
}

// ---------------- fused MFMA message kernel (unchanged from R4) ------------
__global__ __launch_bounds__(512, 4) void k_msg(
    const __bf16* __restrict__ hb,
    const int* __restrict__ bucket, const int* __restrict__ offs,
    const int* __restrict__ src, const int* __restrict__ dst,
    const __bf16* __restrict__ Wsw, const float* __restrict__ b1l,
    const float* __restrict__ b2l,
    float* __restrict__ agg, int n_edges, int nn)
{
    const int t = blockIdx.y;
    const int c0 = offs[nn];
    const int cnt = t ? (n_edges - c0) : c0;
    const int base = t ? c0 : 0;
    const int start = blockIdx.x * TE2;
    if (start >= cnt) return;

    const __bf16* __restrict__ W = Wsw + (size_t)t * 12 * 4096;
    const float*  __restrict__ b1 = b1l + t * H;
    const float*  __restrict__ b2 = b2l + t * H;

    __shared__ __bf16 sW[4096];            // 8 KB weight chunk
    __shared__ float  sMsg[TE2 * MS2];     // 66048 B; sHid aliases per-wave
    __shared__ int    sDstV[TE2];

    const int tid  = threadIdx.x;
    const int lane = tid & 63;
    const int w    = tid >> 6;
    const int r    = lane & 15;
    const int quad = lane >> 4;

    f32x4 wreg[12];
#pragma unroll
    for (int c = 0; c < 12; c++)
        wreg[c] = *(const f32x4*)(W + c * 4096 + tid * 8);

    if (tid < TE2) {
        int i = start + tid;
        sDstV[tid] = (i < cnt) ? dst[bucket[base + i]] : -1;
    }

    int ei = start + w * 16 + r;
    int e = bucket[base + (ei < cnt ? ei : cnt - 1)];
    const __bf16* aps = hb + (size_t)src[e] * H;
    const __bf16* apd = hb + (size_t)dst[e] * H;

    bf16x8 afS[4];
#pragma unroll
    for (int i = 0; i < 4; i++)
        afS[i] = *(const bf16x8*)(aps + i * 32 + quad * 8);

    __syncthreads();

    f32x4 acc[8];
#pragma unroll
    for (int ct = 0; ct < 8; ct++) acc[ct] = (f32x4){0.f, 0.f, 0.f, 0.f};

    bf16x8 afD[4];
#pragma unroll
    for (int kc = 0; kc < 8; kc++) {
        __syncthreads();
        *(f32x4*)(sW + tid * 8) = wreg[kc];
        __syncthreads();
        if (kc == 2) {
#pragma unroll
            for (int i = 0; i < 4; i++)
                afD[i] = *(const bf16x8*)(apd + i * 32 + quad * 8);
        }
        bf16x8 a = (kc < 4) ? afS[kc] : afD[kc - 4];
#pragma unroll
        for (int ct = 0; ct < 8; ct++) {
            bf16x8 b = *(const bf16x8*)(sW + ct * 512 + lane * 8);
            acc[ct] = __builtin_amdgcn_mfma_f32_16x16x32_bf16(a, b, acc[ct], 0, 0, 0);
        }
    }

    __bf16* sHid = (__bf16*)(sMsg + w * 16 * MS2);
#pragma unroll
    for (int ct = 0; ct < 8; ct++) {
        int col = ct * 16 + r;
        float bb = b1[col];
#pragma unroll
        for (int g = 0; g < 4; g++) {
            float v = fmaxf(acc[ct][g] + bb, 0.f);
            sHid[(quad * 4 + g) * HS + col] = (__bf16)v;
        }
    }

    f32x4 acc2[8];
#pragma unroll
    for (int ct = 0; ct < 8; ct++) acc2[ct] = (f32x4){0.f, 0.f, 0.f, 0.f};
#pragma unroll
    for (int kc = 0; kc < 4; kc++) {
        __syncthreads();
        *(f32x4*)(sW + tid * 8) = wreg[8 + kc];
        __syncthreads();
        bf16x8 a = *(const bf16x8*)(sHid + r * HS + kc * 32 + quad * 8);
#pragma unroll
        for (int ct = 0; ct < 8; ct++) {
            bf16x8 b = *(const bf16x8*)(sW + ct * 512 + lane * 8);
            acc2[ct] = __builtin_amdgcn_mfma_f32_16x16x32_bf16(a, b, acc2[ct], 0, 0, 0);
        }
    }

#pragma unroll
    for (int ct = 0; ct < 8; ct++) {
        int col = ct * 16 + r;
        float bb = b2[col];
#pragma unroll
        for (int g = 0; g < 4; g++)
            sMsg[(w * 16 + quad * 4 + g) * MS2 + col] = acc2[ct][g] + bb;
    }
    __syncthreads();

    {
        int j = tid & 127, strip = tid >> 7;
        int e0 = strip * 32;
        float run = 0.f; int curd = -1;
        for (int q = 0; q < 32; q++) {
            int d = sDstV[e0 + q];
            float v = sMsg[(e0 + q) * MS2 + j];
            if (d != curd) {
                if (curd >= 0) atomicAdd(agg + (size_t)curd * H + j, run);
                run = 0.f; curd = d;
            }
            if (d >= 0) run += v;
        }
        if (curd >= 0) atomicAdd(agg + (size_t)curd * H + j, run);
    }
}

// ---------------- GRU cell: split-precision MFMA ---------------------------
// 32 nodes/block, 256 thr (4 waves). gi = agg@Wih, gh = h@Whh as 16x16x32
// bf16 MFMAs with hi/lo Dekker split (3 terms => ~fp32). Wave w: j-tiles
// {2w,2w+1}, m-tiles {0,1}; all 6 gate accs per (node,j) share one lane.
__global__ __launch_bounds__(256, 2) void k_gru(
    float* __restrict__ h, __bf16* __restrict__ hb,
    const float* __restrict__ agg,
    const __bf16* __restrict__ Wg,      // this layer's swizzled hi/lo weights
    const float* __restrict__ bih, const float* __restrict__ bhh,
    int n_nodes)
{
    const int nb = blockIdx.x * 32;
    const int tid = threadIdx.x;
    __shared__ __bf16 sIn[4][32][HS];   // agg_hi, agg_lo, h_hi, h_lo (34.8 KB)

    // ---- stage + split inputs ----
#pragma unroll
    for (int v = 0; v < 4; v++) {
        int idx = tid + 256 * v;            // float4 id, 1024 total
        int e = idx >> 5, c4 = (idx & 31) * 4;
        int n = nb + e;
        float4 av = {0.f, 0.f, 0.f, 0.f}, hv = {0.f, 0.f, 0.f, 0.f};
        if (n < n_nodes) {
            av = *(const float4*)(agg + (size_t)n * H + c4);
            hv = *(const float4*)(h + (size_t)n * H + c4);
        }
        bf16x4 ahi, alo, hhi, hlo;
        float af[4] = {av.x, av.y, av.z, av.w};
        float hf[4] = {hv.x, hv.y, hv.z, hv.w};
#pragma unroll
        for (int c = 0; c < 4; c++) {
            __bf16 ah = (__bf16)af[c]; ahi[c] = ah; alo[c] = (__bf16)(af[c] - (float)ah);
            __bf16 hh = (__bf16)hf[c]; hhi[c] = hh; hlo[c] = (__bf16)(hf[c] - (float)hh);
        }
        *(bf16x4*)&sIn[0][e][c4] = ahi;
        *(bf16x4*)&sIn[1][e][c4] = alo;
        *(bf16x4*)&sIn[2][e][c4] = hhi;
        *(bf16x4*)&sIn[3][e][c4] = hlo;
    }
    __syncthreads();

    const int lane = tid & 63, w = tid >> 6;
    const int r = lane & 15, quad = lane >> 4;
    const int jt0 = w * 2;

    f32x4 acc[2][2][3][2];                 // [m][j][gate][mat]
#pragma unroll
    for (int m = 0; m < 2; m++)
#pragma unroll
        for (int j = 0; j < 2; j++)
#pragma unroll
            for (int g = 0; g < 3; g++)
#pragma unroll
                for (int mat = 0; mat < 2; mat++)
                    acc[m][j][g][mat] = (f32x4){0.f, 0.f, 0.f, 0.f};

#pragma unroll
    for (int kc = 0; kc < 4; kc++) {
        bf16x8 A[2][4];
#pragma unroll
        for (int m = 0; m < 2; m++)
#pragma unroll
            for (int s = 0; s < 4; s++)
                A[m][s] = *(const bf16x8*)&sIn[s][m * 16 + r][kc * 32 + quad * 8];
#pragma unroll
        for (int j = 0; j < 2; j++)
#pragma unroll
        for (int g = 0; g < 3; g++)
#pragma unroll
        for (int mat = 0; mat < 2; mat++) {
            int jtg = g * 8 + jt0 + j;
            bf16x8 bhi = *(const bf16x8*)(Wg +
                ((((size_t)(mat * 2 + 0) * 4 + kc) * 24 + jtg) * 64 + lane) * 8);
            bf16x8 blo = *(const bf16x8*)(Wg +
                ((((size_t)(mat * 2 + 1) * 4 + kc) * 24 + jtg) * 64 + lane) * 8);
            int s = mat * 2;               // A hi index for this mat
#pragma unroll
            for (int m = 0; m < 2; m++) {
                acc[m][j][g][mat] = __builtin_amdgcn_mfma_f32_16x16x32_bf16(
                    A[m][s], bhi, acc[m][j][g][mat], 0, 0, 0);
                acc[m][j][g][mat] = __builtin_amdgcn_mfma_f32_16x16x32_bf16(
                    A[m][s], blo, acc[m][j][g][mat], 0, 0, 0);
                acc[m][j][g][mat] = __builtin_amdgcn_mfma_f32_16x16x32_bf16(
                    A[m][s + 1], bhi, acc[m][j][g][mat], 0, 0, 0);
            }
        }
    }

    // ---- gate epilogue (register-only) ----
#pragma unroll
    for (int m = 0; m < 2; m++)
#pragma unroll
    for (int j = 0; j < 2; j++) {
        int jcol = (jt0 + j) * 16 + r;
        float br_ = bih[jcol], bz_ = bih[128 + jcol], bn_ = bih[256 + jcol];
        float cr = bhh[jcol], cz = bhh[128 + jcol], cn = bhh[256 + jcol];
#pragma unroll
        for (int g4 = 0; g4 < 4; g4++) {
            int n = nb + m * 16 + quad * 4 + g4;
            if (n < n_nodes) {
                float ir = acc[m][j][0][0][g4], hr = acc[m][j][0][1][g4];
                float iz = acc[m][j][1][0][g4], hz = acc[m][j][1][1][g4];
                float in_ = acc[m][j][2][0][g4], hn = acc[m][j][2][1][g4];
                float hold = h[(size_t)n * H + jcol];
                float rr = 1.f / (1.f + expf(-(ir + br_ + hr + cr)));
                float zz = 1.f / (1.f + expf(-(iz + bz_ + hz + cz)));
                float nv = tanhf(in_ + bn_ + rr * (hn + cn));
                float out = (1.f - zz) * nv + zz * hold;
                h[(size_t)n * H + jcol] = out;
                hb[(size_t)n * H + jcol] = (__bf16)out;
            }
        }
    }
}

// ---------------- readout: out = relu(h@Wr1+br1) @ Wr2 + br2 ---------------
__global__ __launch_bounds__(128) void k_readout(
    const float* __restrict__ h, const float* __restrict__ Wr1,
    const float* __restrict__ br1, const float* __restrict__ Wr2,
    const float* __restrict__ br2, float* __restrict__ out, int n_out)
{
    const int n0 = blockIdx.x * 8;
    const int tid = threadIdx.x;     // 128
    __shared__ float sh[8][H];
    __shared__ float sRed[2][8];
    {
        int e = tid >> 4, q = (tid & 15) * 8;
        int n = n0 + e;
        if (n < n_out) {
            const float* hp = h + (size_t)n * H + q;
            *(float4*)&sh[e][q]     = *(const float4*)hp;
            *(float4*)&sh[e][q + 4] = *(const float4*)(hp + 4);
        }
    }
    __syncthreads();

    const int j = tid;
    float bb = br1[j];
    float acc[8];
#pragma unroll
    for (int e = 0; e < 8; e++) acc[e] = bb;
    for (int k = 0; k < H; k++) {
        float wv = Wr1[k * H + j];
#pragma unroll
        for (int e = 0; e < 8; e++) acc[e] += sh[e][k] * wv;
    }
    float w2 = Wr2[j];
    int lane = tid & 63, w = tid >> 6;
#pragma unroll
    for (int e = 0; e < 8; e++) {
        float val = fmaxf(acc[e], 0.f) * w2;
#pragma unroll
        for (int off = 32; off > 0; off >>= 1)
            val += __shfl_down(val, off, 64);
        if (lane == 0) sRed[w][e] = val;
    }
    __syncthreads();
    if (tid < 8 && n0 + tid < n_out)
        out[n0 + tid] = sRed[0][tid] + sRed[1][tid] + br2[0];
}

// ---------------------------------------------------------------------------
extern "C" void kernel_launch(void* const* d_in, const int* in_sizes, int n_in,
                              void* d_out, int out_size, void* d_ws, size_t ws_size,
                              hipStream_t stream)
{
    const float* x      = (const float*)d_in[0];
    const int*   eidx   = (const int*)d_in[1];
    const int*   etype  = (const int*)d_in[2];
    const float* Win    = (const float*)d_in[4];
    const float* bin    = (const float*)d_in[5];
    const float* W1     = (const float*)d_in[6];   // (3,2,256,128)
    const float* b1     = (const float*)d_in[7];   // (3,2,128)
    const float* W2     = (const float*)d_in[8];   // (3,2,128,128)
    const float* b2     = (const float*)d_in[9];   // (3,2,128)
    const float* Wih    = (const float*)d_in[10];  // (3,128,384)
    const float* bih    = (const float*)d_in[11];  // (3,384)
    const float* Whh    = (const float*)d_in[12];  // (3,128,384)
    const float* bhh    = (const float*)d_in[13];  // (3,384)
    const float* Wr1    = (const float*)d_in[14];
    const float* br1    = (const float*)d_in[15];
    const float* Wr2    = (const float*)d_in[16];
    const float* br2    = (const float*)d_in[17];

    const int n_nodes = in_sizes[0] / FEAT;
    const int n_edges = in_sizes[1] / 2;
    const int L = 3;
    const size_t nh = (size_t)n_nodes * H;

    const int* src = eidx;
    const int* dst = eidx + n_edges;

    // workspace carve-up
    float*  h    = (float*)d_ws;                    // 25.6 MB
    float*  agg  = h + nh;                          // 25.6 MB
    __bf16* hb   = (__bf16*)(agg + nh);             // 12.8 MB
    __bf16* Wsw  = hb + nh;                         // 6*12*4096 bf16
    __bf16* Wg   = Wsw + 6 * 12 * 4096;             // 3*WG_PER_LAYER bf16
    int* bucket  = (int*)(Wg + 3 * WG_PER_LAYER);   // n_edges
    int* cnt     = bucket + n_edges;                // 2*nn (also k_place cursors)
    int* offs    = cnt + 2 * n_nodes;               // 2*nn + 1

    hipMemsetAsync(cnt, 0, (size_t)2 * n_nodes * sizeof(int), stream);

    k_wconv<<<(6 * 12 * 4096 + 255) / 256, 256, 0, stream>>>(W1, W2, Wsw);
    k_wgconv<<<(3 * WG_PER_LAYER + 255) / 256, 256, 0, stream>>>(Wih, Whh, Wg);
    k_input<<<((int)nh + 255) / 256, 256, 0, stream>>>(x, Win, bin, h, hb, n_nodes);

    const int eb = (n_edges + 255) / 256;
    k_hist <<<eb, 256, 0, stream>>>(etype, dst, cnt, n_edges, n_nodes);
    k_scan <<<1, 1024, 0, stream>>>(cnt, offs, 2 * n_nodes);
    k_place<<<eb, 256, 0, stream>>>(etype, dst, offs, cnt, bucket, n_edges, n_nodes);

    const dim3 mgrid((n_edges + TE2 - 1) / TE2, 2);
    for (int l = 0; l < L; l++) {
        hipMemsetAsync(agg, 0, nh * sizeof(float), stream);
        k_msg<<<mgrid, 512, 0, stream>>>(
            hb, bucket, offs, src, dst,
            Wsw + (size_t)l * 2 * 12 * 4096,
            b1 + (size_t)l * 2 * H, b2 + (size_t)l * 2 * H,
            agg, n_edges, n_nodes);
        k_gru<<<(n_nodes + 31) / 32, 256, 0, stream>>>(
            h, hb, agg,
            Wg + (size_t)l * WG_PER_LAYER,
            bih + (size_t)l * 384, bhh + (size_t)l * 384,
            n_nodes);
    }

    k_readout<<<(out_size + 7) / 8, 128, 0, stream>>>(
        h, Wr1, br1, Wr2, br2, (float*)d_out, out_size);
}

// Round 8
// 699.209 us; speedup vs baseline: 1.5789x; 1.1013x over previous
//
#include <hip/hip_runtime.h>
#include <math.h>

// ---------------------------------------------------------------------------
// TannerGNN. Round 8: k_gru gets explicit register double-buffering of
// B-fragments (8 waves, 1 j-tile/wave, 12-fragment prefetch burst) — same
// accumulation order as R7 => bit-identical numerics. k_readout 16/block.
// k_msg unchanged from R4.
// N_NODES=50000, N_EDGES=400000, H=128, L=3, T=2, FEAT=4, N_DATA=40000.
// ---------------------------------------------------------------------------

#define H 128
#define TE2 128        // edges per message block (8 waves x 16)
#define MS2 129        // sMsg row stride in f32
#define HS  136        // sHid/sIn row stride in bf16
#define FEAT 4
#define WG_PER_LAYER 196608   // 2 mat * 2 split * 4 kc * 24 jtg * 64 lane * 8

typedef __bf16 bf16x8 __attribute__((ext_vector_type(8)));
typedef __bf16 bf16x4 __attribute__((ext_vector_type(4)));
typedef float  f32x4  __attribute__((ext_vector_type(4)));

// ---------------- input projection: h = relu(x @ W_in + b_in) --------------
__global__ __launch_bounds__(256) void k_input(
    const float* __restrict__ x, const float* __restrict__ Win,
    const float* __restrict__ bin, float* __restrict__ h,
    __bf16* __restrict__ hb, int n_nodes)
{
    int idx = blockIdx.x * 256 + threadIdx.x;
    if (idx >= n_nodes * H) return;
    int n = idx >> 7, j = idx & 127;
    float acc = bin[j];
#pragma unroll
    for (int f = 0; f < FEAT; f++)
        acc += x[n * FEAT + f] * Win[f * H + j];
    float v = fmaxf(acc, 0.f);
    h[idx] = v;
    hb[idx] = (__bf16)v;
}

// ---------------- message-weight conversion: bf16, MFMA-fragment order -----
__global__ __launch_bounds__(256) void k_wconv(
    const float* __restrict__ W1, const float* __restrict__ W2,
    __bf16* __restrict__ Wsw)
{
    int gid = blockIdx.x * 256 + threadIdx.x;
    const int per_lt = 12 * 4096;
    if (gid >= 6 * per_lt) return;
    int lt = gid / per_lt, rem = gid % per_lt;
    int chunk = rem >> 12;
    int within = rem & 4095;
    int ct = within >> 9;
    int lane = (within >> 3) & 63;
    int j = within & 7;
    int r = lane & 15, quad = lane >> 4;
    int n = ct * 16 + r;
    float v;
    if (chunk < 8) {
        int k = chunk * 32 + quad * 8 + j;
        v = W1[((size_t)lt * 256 + k) * 128 + n];
    } else {
        int k = (chunk - 8) * 32 + quad * 8 + j;
        v = W2[((size_t)lt * 128 + k) * 128 + n];
    }
    Wsw[gid] = (__bf16)v;
}

// ---------------- GRU-weight conversion: hi/lo split, B-fragment order -----
// Per layer WG_PER_LAYER elems: ((((mat*2+split)*4 + kc)*24 + jtg)*64+lane)*8+t
__global__ __launch_bounds__(256) void k_wgconv(
    const float* __restrict__ Wih, const float* __restrict__ Whh,
    __bf16* __restrict__ Wg)
{
    int gid = blockIdx.x * 256 + threadIdx.x;
    if (gid >= 3 * WG_PER_LAYER) return;
    int layer = gid / WG_PER_LAYER, rem = gid % WG_PER_LAYER;
    int t = rem & 7;
    int lane = (rem >> 3) & 63;
    int jtg = (rem >> 9) % 24;
    int mk = rem / 12288;          // (mat*2+split)*4 + kc, 0..15
    int kc = mk & 3;
    int msplit = mk >> 2;          // 0..3
    int mat = msplit >> 1, split = msplit & 1;
    int r = lane & 15, quad = lane >> 4;
    int k = kc * 32 + quad * 8 + t;
    int n = jtg * 16 + r;
    const float* W = (mat ? Whh : Wih) + (size_t)layer * 128 * 384;
    float v = W[(size_t)k * 384 + n];
    __bf16 hi = (__bf16)v;
    Wg[gid] = split ? (__bf16)(v - (float)hi) : hi;
}

// ---------------- counting sort by key = type*nn + dst ---------------------
__global__ __launch_bounds__(256) void k_hist(
    const int* __restrict__ et, const int* __restrict__ dst,
    int* __restrict__ cnt, int n_edges, int nn)
{
    int i = blockIdx.x * 256 + threadIdx.x;
    if (i < n_edges) atomicAdd(&cnt[et[i] * nn + dst[i]], 1);
}

__global__ __launch_bounds__(1024) void k_scan(
    const int* __restrict__ cnt, int* __restrict__ offs, int n)
{
    __shared__ int sW[16];
    __shared__ int sBase;
    if (threadIdx.x == 0) sBase = 0;
    __syncthreads();
    int lane = threadIdx.x & 63, w = threadIdx.x >> 6;
    for (int c = 0; c < n; c += 1024) {
        int idx = c + threadIdx.x;
        int v = (idx < n) ? cnt[idx] : 0;
        int orig = v;
#pragma unroll
        for (int off = 1; off < 64; off <<= 1) {
            int t = __shfl_up(v, off, 64);
            if (lane >= off) v += t;
        }
        if (lane == 63) sW[w] = v;
        __syncthreads();
        if (w == 0 && lane < 16) {
            int x = sW[lane];
#pragma unroll
            for (int off = 1; off < 16; off <<= 1) {
                int t = __shfl_up(x, off, 64);
                if (lane >= off) x += t;
            }
            sW[lane] = x;
        }
        __syncthreads();
        int wbase = w ? sW[w - 1] : 0;
        int base = sBase;
        if (idx < n) offs[idx] = base + wbase + v - orig;
        __syncthreads();
        if (threadIdx.x == 0) sBase = base + sW[15];
        __syncthreads();
    }
    if (threadIdx.x == 0) offs[n] = sBase;
}

// claims slots by decrementing cnt (cnt is dead after k_scan; ends all-zero)
__global__ __launch_bounds__(256) void k_place(
    const int* __restrict__ et, const int* __restrict__ dst,
    const int* __restrict__ offs, int* __restrict__ cnt,
    int* __restrict__ bucket, int n_edges, int nn)
{
    int i = blockIdx.x * 256 + threadIdx.x;
    if (i < n_edges) {
        int key = et[i] * nn + dst[i];
        int p = atomicAdd(&cnt[key], -1) - 1;
        bucket[offs[key] + p] = i;
    }
}

// ---------------- fused MFMA message kernel (unchanged from R4) ------------
__global__ __launch_bounds__(512, 4) void k_msg(
    const __bf16* __restrict__ hb,
    const int* __restrict__ bucket, const int* __restrict__ offs,
    const int* __restrict__ src, const int* __restrict__ dst,
    const __bf16* __restrict__ Wsw, const float* __restrict__ b1l,
    const float* __restrict__ b2l,
    float* __restrict__ agg, int n_edges, int nn)
{
    const int t = blockIdx.y;
    const int c0 = offs[nn];
    const int cnt = t ? (n_edges - c0) : c0;
    const int base = t ? c0 : 0;
    const int start = blockIdx.x * TE2;
    if (start >= cnt) return;

    const __bf16* __restrict__ W = Wsw + (size_t)t * 12 * 4096;
    const float*  __restrict__ b1 = b1l + t * H;
    const float*  __restrict__ b2 = b2l + t * H;

    __shared__ __bf16 sW[4096];            // 8 KB weight chunk
    __shared__ float  sMsg[TE2 * MS2];     // 66048 B; sHid aliases per-wave
    __shared__ int    sDstV[TE2];

    const int tid  = threadIdx.x;
    const int lane = tid & 63;
    const int w    = tid >> 6;
    const int r    = lane & 15;
    const int quad = lane >> 4;

    f32x4 wreg[12];
#pragma unroll
    for (int c = 0; c < 12; c++)
        wreg[c] = *(const f32x4*)(W + c * 4096 + tid * 8);

    if (tid < TE2) {
        int i = start + tid;
        sDstV[tid] = (i < cnt) ? dst[bucket[base + i]] : -1;
    }

    int ei = start + w * 16 + r;
    int e = bucket[base + (ei < cnt ? ei : cnt - 1)];
    const __bf16* aps = hb + (size_t)src[e] * H;
    const __bf16* apd = hb + (size_t)dst[e] * H;

    bf16x8 afS[4];
#pragma unroll
    for (int i = 0; i < 4; i++)
        afS[i] = *(const bf16x8*)(aps + i * 32 + quad * 8);

    __syncthreads();

    f32x4 acc[8];
#pragma unroll
    for (int ct = 0; ct < 8; ct++) acc[ct] = (f32x4){0.f, 0.f, 0.f, 0.f};

    bf16x8 afD[4];
#pragma unroll
    for (int kc = 0; kc < 8; kc++) {
        __syncthreads();
        *(f32x4*)(sW + tid * 8) = wreg[kc];
        __syncthreads();
        if (kc == 2) {
#pragma unroll
            for (int i = 0; i < 4; i++)
                afD[i] = *(const bf16x8*)(apd + i * 32 + quad * 8);
        }
        bf16x8 a = (kc < 4) ? afS[kc] : afD[kc - 4];
#pragma unroll
        for (int ct = 0; ct < 8; ct++) {
            bf16x8 b = *(const bf16x8*)(sW + ct * 512 + lane * 8);
            acc[ct] = __builtin_amdgcn_mfma_f32_16x16x32_bf16(a, b, acc[ct], 0, 0, 0);
        }
    }

    __bf16* sHid = (__bf16*)(sMsg + w * 16 * MS2);
#pragma unroll
    for (int ct = 0; ct < 8; ct++) {
        int col = ct * 16 + r;
        float bb = b1[col];
#pragma unroll
        for (int g = 0; g < 4; g++) {
            float v = fmaxf(acc[ct][g] + bb, 0.f);
            sHid[(quad * 4 + g) * HS + col] = (__bf16)v;
        }
    }

    f32x4 acc2[8];
#pragma unroll
    for (int ct = 0; ct < 8; ct++) acc2[ct] = (f32x4){0.f, 0.f, 0.f, 0.f};
#pragma unroll
    for (int kc = 0; kc < 4; kc++) {
        __syncthreads();
        *(f32x4*)(sW + tid * 8) = wreg[8 + kc];
        __syncthreads();
        bf16x8 a = *(const bf16x8*)(sHid + r * HS + kc * 32 + quad * 8);
#pragma unroll
        for (int ct = 0; ct < 8; ct++) {
            bf16x8 b = *(const bf16x8*)(sW + ct * 512 + lane * 8);
            acc2[ct] = __builtin_amdgcn_mfma_f32_16x16x32_bf16(a, b, acc2[ct], 0, 0, 0);
        }
    }

#pragma unroll
    for (int ct = 0; ct < 8; ct++) {
        int col = ct * 16 + r;
        float bb = b2[col];
#pragma unroll
        for (int g = 0; g < 4; g++)
            sMsg[(w * 16 + quad * 4 + g) * MS2 + col] = acc2[ct][g] + bb;
    }
    __syncthreads();

    {
        int j = tid & 127, strip = tid >> 7;
        int e0 = strip * 32;
        float run = 0.f; int curd = -1;
        for (int q = 0; q < 32; q++) {
            int d = sDstV[e0 + q];
            float v = sMsg[(e0 + q) * MS2 + j];
            if (d != curd) {
                if (curd >= 0) atomicAdd(agg + (size_t)curd * H + j, run);
                run = 0.f; curd = d;
            }
            if (d >= 0) run += v;
        }
        if (curd >= 0) atomicAdd(agg + (size_t)curd * H + j, run);
    }
}

// ---------------- GRU cell: split-precision MFMA, double-buffered B --------
// 32 nodes/block, 512 thr (8 waves). Wave w owns base j-tile jt=w (16 cols),
// gate tiles jtg = g*8+w. Per kc: 12 B fragments (mat2 x g3 x split2) in an
// explicit 2-deep register buffer, prefetched one kc ahead. Accumulation
// order identical to R7 => bit-identical output.
__global__ __launch_bounds__(512, 2) void k_gru(
    float* __restrict__ h, __bf16* __restrict__ hb,
    const float* __restrict__ agg,
    const __bf16* __restrict__ Wg,      // this layer's swizzled hi/lo weights
    const float* __restrict__ bih, const float* __restrict__ bhh,
    int n_nodes)
{
    const int nb = blockIdx.x * 32;
    const int tid = threadIdx.x;
    __shared__ __bf16 sIn[4][32][HS];   // agg_hi, agg_lo, h_hi, h_lo (34.8 KB)

    // ---- stage + split inputs (1024 float4s, 2 per thread) ----
#pragma unroll
    for (int v = 0; v < 2; v++) {
        int idx = tid + 512 * v;
        int e = idx >> 5, c4 = (idx & 31) * 4;
        int n = nb + e;
        float4 av = {0.f, 0.f, 0.f, 0.f}, hv = {0.f, 0.f, 0.f, 0.f};
        if (n < n_nodes) {
            av = *(const float4*)(agg + (size_t)n * H + c4);
            hv = *(const float4*)(h + (size_t)n * H + c4);
        }
        bf16x4 ahi, alo, hhi, hlo;
        float af[4] = {av.x, av.y, av.z, av.w};
        float hf[4] = {hv.x, hv.y, hv.z, hv.w};
#pragma unroll
        for (int c = 0; c < 4; c++) {
            __bf16 ah = (__bf16)af[c]; ahi[c] = ah; alo[c] = (__bf16)(af[c] - (float)ah);
            __bf16 hh = (__bf16)hf[c]; hhi[c] = hh; hlo[c] = (__bf16)(hf[c] - (float)hh);
        }
        *(bf16x4*)&sIn[0][e][c4] = ahi;
        *(bf16x4*)&sIn[1][e][c4] = alo;
        *(bf16x4*)&sIn[2][e][c4] = hhi;
        *(bf16x4*)&sIn[3][e][c4] = hlo;
    }
    __syncthreads();

    const int lane = tid & 63, w = tid >> 6;     // w: 0..7
    const int r = lane & 15, quad = lane >> 4;
    const int jt = w;

    f32x4 acc[2][3][2];                  // [m][gate][mat]
#pragma unroll
    for (int m = 0; m < 2; m++)
#pragma unroll
        for (int g = 0; g < 3; g++)
#pragma unroll
            for (int mat = 0; mat < 2; mat++)
                acc[m][g][mat] = (f32x4){0.f, 0.f, 0.f, 0.f};

    // B-fragment double buffer: [buf][mat*6 + g*2 + split]
    bf16x8 B[2][12];
#pragma unroll
    for (int mat = 0; mat < 2; mat++)
#pragma unroll
    for (int g = 0; g < 3; g++)
#pragma unroll
    for (int sp = 0; sp < 2; sp++)
        B[0][mat * 6 + g * 2 + sp] = *(const bf16x8*)(Wg +
            ((((size_t)(mat * 2 + sp) * 4 + 0) * 24 + (g * 8 + jt)) * 64 + lane) * 8);

#pragma unroll
    for (int kc = 0; kc < 4; kc++) {
        const int cur = kc & 1, nxt = cur ^ 1;
        if (kc < 3) {   // prefetch next kc's 12 fragments (one burst)
#pragma unroll
            for (int mat = 0; mat < 2; mat++)
#pragma unroll
            for (int g = 0; g < 3; g++)
#pragma unroll
            for (int sp = 0; sp < 2; sp++)
                B[nxt][mat * 6 + g * 2 + sp] = *(const bf16x8*)(Wg +
                    ((((size_t)(mat * 2 + sp) * 4 + (kc + 1)) * 24 + (g * 8 + jt)) * 64 + lane) * 8);
        }
        bf16x8 A[2][4];
#pragma unroll
        for (int m = 0; m < 2; m++)
#pragma unroll
            for (int s = 0; s < 4; s++)
                A[m][s] = *(const bf16x8*)&sIn[s][m * 16 + r][kc * 32 + quad * 8];
#pragma unroll
        for (int g = 0; g < 3; g++)
#pragma unroll
        for (int mat = 0; mat < 2; mat++) {
            bf16x8 bhi = B[cur][mat * 6 + g * 2 + 0];
            bf16x8 blo = B[cur][mat * 6 + g * 2 + 1];
            int s = mat * 2;
#pragma unroll
            for (int m = 0; m < 2; m++) {
                acc[m][g][mat] = __builtin_amdgcn_mfma_f32_16x16x32_bf16(
                    A[m][s], bhi, acc[m][g][mat], 0, 0, 0);
                acc[m][g][mat] = __builtin_amdgcn_mfma_f32_16x16x32_bf16(
                    A[m][s], blo, acc[m][g][mat], 0, 0, 0);
                acc[m][g][mat] = __builtin_amdgcn_mfma_f32_16x16x32_bf16(
                    A[m][s + 1], bhi, acc[m][g][mat], 0, 0, 0);
            }
        }
    }

    // ---- gate epilogue (register-only) ----
    const int jcol = jt * 16 + r;
    float br_ = bih[jcol], bz_ = bih[128 + jcol], bn_ = bih[256 + jcol];
    float cr = bhh[jcol], cz = bhh[128 + jcol], cn = bhh[256 + jcol];
#pragma unroll
    for (int m = 0; m < 2; m++)
#pragma unroll
    for (int g4 = 0; g4 < 4; g4++) {
        int n = nb + m * 16 + quad * 4 + g4;
        if (n < n_nodes) {
            float ir = acc[m][0][0][g4], hr = acc[m][0][1][g4];
            float iz = acc[m][1][0][g4], hz = acc[m][1][1][g4];
            float in_ = acc[m][2][0][g4], hn = acc[m][2][1][g4];
            float hold = h[(size_t)n * H + jcol];
            float rr = 1.f / (1.f + expf(-(ir + br_ + hr + cr)));
            float zz = 1.f / (1.f + expf(-(iz + bz_ + hz + cz)));
            float nv = tanhf(in_ + bn_ + rr * (hn + cn));
            float out = (1.f - zz) * nv + zz * hold;
            h[(size_t)n * H + jcol] = out;
            hb[(size_t)n * H + jcol] = (__bf16)out;
        }
    }
}

// ---------------- readout: out = relu(h@Wr1+br1) @ Wr2 + br2 ---------------
__global__ __launch_bounds__(128) void k_readout(
    const float* __restrict__ h, const float* __restrict__ Wr1,
    const float* __restrict__ br1, const float* __restrict__ Wr2,
    const float* __restrict__ br2, float* __restrict__ out, int n_out)
{
    const int n0 = blockIdx.x * 16;
    const int tid = threadIdx.x;     // 128
    __shared__ float sh[16][H];      // 8 KB
    __shared__ float sRed[2][16];
    {
#pragma unroll
        for (int v = 0; v < 4; v++) {
            int idx = tid + 128 * v;          // float4 id, 512 total
            int e = idx >> 5, q = (idx & 31) * 4;
            int n = n0 + e;
            if (n < n_out)
                *(float4*)&sh[e][q] = *(const float4*)(h + (size_t)n * H + q);
        }
    }
    __syncthreads();

    const int j = tid;
    float bb = br1[j];
    float acc[16];
#pragma unroll
    for (int e = 0; e < 16; e++) acc[e] = bb;
    for (int k = 0; k < H; k++) {
        float wv = Wr1[k * H + j];
#pragma unroll
        for (int e = 0; e < 16; e++) acc[e] += sh[e][k] * wv;
    }
    float w2 = Wr2[j];
    int lane = tid & 63, w = tid >> 6;
#pragma unroll
    for (int e = 0; e < 16; e++) {
        float val = fmaxf(acc[e], 0.f) * w2;
#pragma unroll
        for (int off = 32; off > 0; off >>= 1)
            val += __shfl_down(val, off, 64);
        if (lane == 0) sRed[w][e] = val;
    }
    __syncthreads();
    if (tid < 16 && n0 + tid < n_out)
        out[n0 + tid] = sRed[0][tid] + sRed[1][tid] + br2[0];
}

// ---------------------------------------------------------------------------
extern "C" void kernel_launch(void* const* d_in, const int* in_sizes, int n_in,
                              void* d_out, int out_size, void* d_ws, size_t ws_size,
                              hipStream_t stream)
{
    const float* x      = (const float*)d_in[0];
    const int*   eidx   = (const int*)d_in[1];
    const int*   etype  = (const int*)d_in[2];
    const float* Win    = (const float*)d_in[4];
    const float* bin    = (const float*)d_in[5];
    const float* W1     = (const float*)d_in[6];   // (3,2,256,128)
    const float* b1     = (const float*)d_in[7];   // (3,2,128)
    const float* W2     = (const float*)d_in[8];   // (3,2,128,128)
    const float* b2     = (const float*)d_in[9];   // (3,2,128)
    const float* Wih    = (const float*)d_in[10];  // (3,128,384)
    const float* bih    = (const float*)d_in[11];  // (3,384)
    const float* Whh    = (const float*)d_in[12];  // (3,128,384)
    const float* bhh    = (const float*)d_in[13];  // (3,384)
    const float* Wr1    = (const float*)d_in[14];
    const float* br1    = (const float*)d_in[15];
    const float* Wr2    = (const float*)d_in[16];
    const float* br2    = (const float*)d_in[17];

    const int n_nodes = in_sizes[0] / FEAT;
    const int n_edges = in_sizes[1] / 2;
    const int L = 3;
    const size_t nh = (size_t)n_nodes * H;

    const int* src = eidx;
    const int* dst = eidx + n_edges;

    // workspace carve-up
    float*  h    = (float*)d_ws;                    // 25.6 MB
    float*  agg  = h + nh;                          // 25.6 MB
    __bf16* hb   = (__bf16*)(agg + nh);             // 12.8 MB
    __bf16* Wsw  = hb + nh;                         // 6*12*4096 bf16
    __bf16* Wg   = Wsw + 6 * 12 * 4096;             // 3*WG_PER_LAYER bf16
    int* bucket  = (int*)(Wg + 3 * WG_PER_LAYER);   // n_edges
    int* cnt     = bucket + n_edges;                // 2*nn (also k_place cursors)
    int* offs    = cnt + 2 * n_nodes;               // 2*nn + 1

    hipMemsetAsync(cnt, 0, (size_t)2 * n_nodes * sizeof(int), stream);

    k_wconv<<<(6 * 12 * 4096 + 255) / 256, 256, 0, stream>>>(W1, W2, Wsw);
    k_wgconv<<<(3 * WG_PER_LAYER + 255) / 256, 256, 0, stream>>>(Wih, Whh, Wg);
    k_input<<<((int)nh + 255) / 256, 256, 0, stream>>>(x, Win, bin, h, hb, n_nodes);

    const int eb = (n_edges + 255) / 256;
    k_hist <<<eb, 256, 0, stream>>>(etype, dst, cnt, n_edges, n_nodes);
    k_scan <<<1, 1024, 0, stream>>>(cnt, offs, 2 * n_nodes);
    k_place<<<eb, 256, 0, stream>>>(etype, dst, offs, cnt, bucket, n_edges, n_nodes);

    const dim3 mgrid((n_edges + TE2 - 1) / TE2, 2);
    for (int l = 0; l < L; l++) {
        hipMemsetAsync(agg, 0, nh * sizeof(float), stream);
        k_msg<<<mgrid, 512, 0, stream>>>(
            hb, bucket, offs, src, dst,
            Wsw + (size_t)l * 2 * 12 * 4096,
            b1 + (size_t)l * 2 * H, b2 + (size_t)l * 2 * H,
            agg, n_edges, n_nodes);
        k_gru<<<(n_nodes + 31) / 32, 512, 0, stream>>>(
            h, hb, agg,
            Wg + (size_t)l * WG_PER_LAYER,
            bih + (size_t)l * 384, bhh + (size_t)l * 384,
            n_nodes);
    }

    k_readout<<<(out_size + 15) / 16, 128, 0, stream>>>(
        h, Wr1, br1, Wr2, br2, (float*)d_out, out_size);
}

// Round 9
// 609.567 us; speedup vs baseline: 1.8111x; 1.1471x over previous
//
#include <hip/hip_runtime.h>
#include <math.h>

// ---------------------------------------------------------------------------
// TannerGNN. Round 9: parallel 3-kernel scan (was 93us single-block);
// k_msg transposed MFMA operands (bit-identical math, vectorized LDS
// epilogues); agg zeroing fused into k_gru. k_gru core unchanged from R8.
// N_NODES=50000, N_EDGES=400000, H=128, L=3, T=2, FEAT=4, N_DATA=40000.
// ---------------------------------------------------------------------------

#define H 128
#define TE2 128        // edges per message block (8 waves x 16)
#define MS2 132        // sMsg row stride in f32 (16B-aligned rows)
#define HS  136        // sHid/sIn row stride in bf16
#define FEAT 4
#define WG_PER_LAYER 196608   // 2 mat * 2 split * 4 kc * 24 jtg * 64 lane * 8

typedef __bf16 bf16x8 __attribute__((ext_vector_type(8)));
typedef __bf16 bf16x4 __attribute__((ext_vector_type(4)));
typedef float  f32x4  __attribute__((ext_vector_type(4)));

// ---------------- input projection: h = relu(x @ W_in + b_in) --------------
__global__ __launch_bounds__(256) void k_input(
    const float* __restrict__ x, const float* __restrict__ Win,
    const float* __restrict__ bin, float* __restrict__ h,
    __bf16* __restrict__ hb, int n_nodes)
{
    int idx = blockIdx.x * 256 + threadIdx.x;
    if (idx >= n_nodes * H) return;
    int n = idx >> 7, j = idx & 127;
    float acc = bin[j];
#pragma unroll
    for (int f = 0; f < FEAT; f++)
        acc += x[n * FEAT + f] * Win[f * H + j];
    float v = fmaxf(acc, 0.f);
    h[idx] = v;
    hb[idx] = (__bf16)v;
}

// ---------------- message-weight conversion: bf16, MFMA-fragment order -----
__global__ __launch_bounds__(256) void k_wconv(
    const float* __restrict__ W1, const float* __restrict__ W2,
    __bf16* __restrict__ Wsw)
{
    int gid = blockIdx.x * 256 + threadIdx.x;
    const int per_lt = 12 * 4096;
    if (gid >= 6 * per_lt) return;
    int lt = gid / per_lt, rem = gid % per_lt;
    int chunk = rem >> 12;
    int within = rem & 4095;
    int ct = within >> 9;
    int lane = (within >> 3) & 63;
    int j = within & 7;
    int r = lane & 15, quad = lane >> 4;
    int n = ct * 16 + r;
    float v;
    if (chunk < 8) {
        int k = chunk * 32 + quad * 8 + j;
        v = W1[((size_t)lt * 256 + k) * 128 + n];
    } else {
        int k = (chunk - 8) * 32 + quad * 8 + j;
        v = W2[((size_t)lt * 128 + k) * 128 + n];
    }
    Wsw[gid] = (__bf16)v;
}

// ---------------- GRU-weight conversion: hi/lo split, B-fragment order -----
__global__ __launch_bounds__(256) void k_wgconv(
    const float* __restrict__ Wih, const float* __restrict__ Whh,
    __bf16* __restrict__ Wg)
{
    int gid = blockIdx.x * 256 + threadIdx.x;
    if (gid >= 3 * WG_PER_LAYER) return;
    int layer = gid / WG_PER_LAYER, rem = gid % WG_PER_LAYER;
    int t = rem & 7;
    int lane = (rem >> 3) & 63;
    int jtg = (rem >> 9) % 24;
    int mk = rem / 12288;          // (mat*2+split)*4 + kc, 0..15
    int kc = mk & 3;
    int msplit = mk >> 2;          // 0..3
    int mat = msplit >> 1, split = msplit & 1;
    int r = lane & 15, quad = lane >> 4;
    int k = kc * 32 + quad * 8 + t;
    int n = jtg * 16 + r;
    const float* W = (mat ? Whh : Wih) + (size_t)layer * 128 * 384;
    float v = W[(size_t)k * 384 + n];
    __bf16 hi = (__bf16)v;
    Wg[gid] = split ? (__bf16)(v - (float)hi) : hi;
}

// ---------------- counting sort by key = type*nn + dst ---------------------
__global__ __launch_bounds__(256) void k_hist(
    const int* __restrict__ et, const int* __restrict__ dst,
    int* __restrict__ cnt, int n_edges, int nn)
{
    int i = blockIdx.x * 256 + threadIdx.x;
    if (i < n_edges) atomicAdd(&cnt[et[i] * nn + dst[i]], 1);
}

// parallel scan, stage 1: per-block (1024-elem) sums
__global__ __launch_bounds__(1024) void k_scan1(
    const int* __restrict__ cnt, int* __restrict__ bsum, int n)
{
    int i = blockIdx.x * 1024 + threadIdx.x;
    int v = (i < n) ? cnt[i] : 0;
#pragma unroll
    for (int off = 32; off > 0; off >>= 1) v += __shfl_down(v, off, 64);
    __shared__ int ws[16];
    int lane = threadIdx.x & 63, w = threadIdx.x >> 6;
    if (lane == 0) ws[w] = v;
    __syncthreads();
    if (threadIdx.x < 16) {
        int x = ws[threadIdx.x];
#pragma unroll
        for (int off = 8; off > 0; off >>= 1) x += __shfl_down(x, off, 64);
        if (threadIdx.x == 0) bsum[blockIdx.x] = x;
    }
}

// stage 2: exclusive scan of block sums (nb <= 128), writes offs[n] = total
__global__ __launch_bounds__(128) void k_scan2(
    int* __restrict__ bsum, int* __restrict__ offs, int nb, int n)
{
    int lane = threadIdx.x & 63, w = threadIdx.x >> 6;
    int v = (threadIdx.x < nb) ? bsum[threadIdx.x] : 0;
    int orig = v;
#pragma unroll
    for (int off = 1; off < 64; off <<= 1) {
        int t = __shfl_up(v, off, 64);
        if (lane >= off) v += t;
    }
    __shared__ int w0sum;
    if (threadIdx.x == 63) w0sum = v;
    __syncthreads();
    int ex = v - orig + (w ? w0sum : 0);
    if (threadIdx.x < nb) bsum[threadIdx.x] = ex;
    if (threadIdx.x == nb - 1) offs[n] = ex + orig;
}

// stage 3: per-block exclusive scan + block base
__global__ __launch_bounds__(1024) void k_scan3(
    const int* __restrict__ cnt, const int* __restrict__ bsum,
    int* __restrict__ offs, int n)
{
    int i = blockIdx.x * 1024 + threadIdx.x;
    int v = (i < n) ? cnt[i] : 0;
    int orig = v;
    int lane = threadIdx.x & 63, w = threadIdx.x >> 6;
#pragma unroll
    for (int off = 1; off < 64; off <<= 1) {
        int t = __shfl_up(v, off, 64);
        if (lane >= off) v += t;
    }
    __shared__ int ws[16];
    if (lane == 63) ws[w] = v;
    __syncthreads();
    if (threadIdx.x < 16) {
        int x = ws[threadIdx.x];
#pragma unroll
        for (int off = 1; off < 16; off <<= 1) {
            int t = __shfl_up(x, off, 64);
            if (lane >= off) x += t;
        }
        ws[threadIdx.x] = x;
    }
    __syncthreads();
    int wbase = w ? ws[w - 1] : 0;
    if (i < n) offs[i] = bsum[blockIdx.x] + wbase + v - orig;
}

// claims slots by decrementing cnt (cnt is dead after scan; ends all-zero)
__global__ __launch_bounds__(256) void k_place(
    const int* __restrict__ et, const int* __restrict__ dst,
    const int* __restrict__ offs, int* __restrict__ cnt,
    int* __restrict__ bucket, int n_edges, int nn)
{
    int i = blockIdx.x * 256 + threadIdx.x;
    if (i < n_edges) {
        int key = et[i] * nn + dst[i];
        int p = atomicAdd(&cnt[key], -1) - 1;
        bucket[offs[key] + p] = i;
    }
}

// ---------------- fused MFMA message kernel (transposed operands) ----------
// Block = 128 dst-sorted edges of one type, 8 waves; wave w owns 16 edges.
// MFMA computes (cat@W1)^T and (hid@W2)^T: A = weight fragment (same bytes
// as before), B = per-edge fragment. Products commute, same K-tree =>
// bit-identical results; C-layout (col=edge, row=feat) vectorizes epilogues.
__global__ __launch_bounds__(512, 4) void k_msg(
    const __bf16* __restrict__ hb,
    const int* __restrict__ bucket, const int* __restrict__ offs,
    const int* __restrict__ src, const int* __restrict__ dst,
    const __bf16* __restrict__ Wsw, const float* __restrict__ b1l,
    const float* __restrict__ b2l,
    float* __restrict__ agg, int n_edges, int nn)
{
    const int t = blockIdx.y;
    const int c0 = offs[nn];
    const int cnt = t ? (n_edges - c0) : c0;
    const int base = t ? c0 : 0;
    const int start = blockIdx.x * TE2;
    if (start >= cnt) return;

    const __bf16* __restrict__ W = Wsw + (size_t)t * 12 * 4096;
    const float*  __restrict__ b1 = b1l + t * H;
    const float*  __restrict__ b2 = b2l + t * H;

    __shared__ __bf16 sW[4096];            // 8 KB weight chunk
    __shared__ float  sMsg[TE2 * MS2];     // 67584 B; sHid aliases per-wave
    __shared__ int    sDstV[TE2];

    const int tid  = threadIdx.x;
    const int lane = tid & 63;
    const int w    = tid >> 6;
    const int r    = lane & 15;
    const int quad = lane >> 4;

    f32x4 wreg[12];
#pragma unroll
    for (int c = 0; c < 12; c++)
        wreg[c] = *(const f32x4*)(W + c * 4096 + tid * 8);

    if (tid < TE2) {
        int i = start + tid;
        sDstV[tid] = (i < cnt) ? dst[bucket[base + i]] : -1;
    }

    int ei = start + w * 16 + r;
    int e = bucket[base + (ei < cnt ? ei : cnt - 1)];
    const __bf16* aps = hb + (size_t)src[e] * H;
    const __bf16* apd = hb + (size_t)dst[e] * H;

    bf16x8 afS[4];
#pragma unroll
    for (int i = 0; i < 4; i++)
        afS[i] = *(const bf16x8*)(aps + i * 32 + quad * 8);

    __syncthreads();

    // ---- Phase A: hidT = (cat @ W1)^T, K=256 in 8 chunks ----
    f32x4 acc[8];
#pragma unroll
    for (int ct = 0; ct < 8; ct++) acc[ct] = (f32x4){0.f, 0.f, 0.f, 0.f};

    bf16x8 afD[4];
#pragma unroll
    for (int kc = 0; kc < 8; kc++) {
        __syncthreads();
        *(f32x4*)(sW + tid * 8) = wreg[kc];
        __syncthreads();
        if (kc == 2) {
#pragma unroll
            for (int i = 0; i < 4; i++)
                afD[i] = *(const bf16x8*)(apd + i * 32 + quad * 8);
        }
        bf16x8 b = (kc < 4) ? afS[kc] : afD[kc - 4];
#pragma unroll
        for (int ct = 0; ct < 8; ct++) {
            bf16x8 a = *(const bf16x8*)(sW + ct * 512 + lane * 8);
            acc[ct] = __builtin_amdgcn_mfma_f32_16x16x32_bf16(a, b, acc[ct], 0, 0, 0);
        }
    }

    // epilogue A: bias + relu -> bf16 -> sHid[edge=r][feat] (own-wave strip)
    __bf16* sHid = (__bf16*)(sMsg + w * 16 * MS2);   // 16 rows x HS stride
#pragma unroll
    for (int ct = 0; ct < 8; ct++) {
        f32x4 bb4 = *(const f32x4*)(b1 + ct * 16 + quad * 4);
        bf16x4 hv;
#pragma unroll
        for (int g = 0; g < 4; g++)
            hv[g] = (__bf16)fmaxf(acc[ct][g] + bb4[g], 0.f);
        *(bf16x4*)(sHid + r * HS + ct * 16 + quad * 4) = hv;
    }

    // ---- Phase B: msgT = (hid @ W2)^T, K=128 in 4 chunks ----
    f32x4 acc2[8];
#pragma unroll
    for (int ct = 0; ct < 8; ct++) acc2[ct] = (f32x4){0.f, 0.f, 0.f, 0.f};
#pragma unroll
    for (int kc = 0; kc < 4; kc++) {
        __syncthreads();
        *(f32x4*)(sW + tid * 8) = wreg[8 + kc];
        __syncthreads();
        bf16x8 b = *(const bf16x8*)(sHid + r * HS + kc * 32 + quad * 8);
#pragma unroll
        for (int ct = 0; ct < 8; ct++) {
            bf16x8 a = *(const bf16x8*)(sW + ct * 512 + lane * 8);
            acc2[ct] = __builtin_amdgcn_mfma_f32_16x16x32_bf16(a, b, acc2[ct], 0, 0, 0);
        }
    }

    // ---- Phase C: msgs (+bias) -> sMsg[edge = 16w+r][feat], vectorized ----
#pragma unroll
    for (int ct = 0; ct < 8; ct++) {
        f32x4 bb4 = *(const f32x4*)(b2 + ct * 16 + quad * 4);
        f32x4 mv;
#pragma unroll
        for (int g = 0; g < 4; g++)
            mv[g] = acc2[ct][g] + bb4[g];
        *(f32x4*)(sMsg + (w * 16 + r) * MS2 + ct * 16 + quad * 4) = mv;
    }
    __syncthreads();

    // segmented reduction over dst-sorted rows; one atomic per run per col
    {
        int j = tid & 127, strip = tid >> 7;
        int e0 = strip * 32;
        float run = 0.f; int curd = -1;
        for (int q = 0; q < 32; q++) {
            int d = sDstV[e0 + q];
            float v = sMsg[(e0 + q) * MS2 + j];
            if (d != curd) {
                if (curd >= 0) atomicAdd(agg + (size_t)curd * H + j, run);
                run = 0.f; curd = d;
            }
            if (d >= 0) run += v;
        }
        if (curd >= 0) atomicAdd(agg + (size_t)curd * H + j, run);
    }
}

// ---------------- GRU cell: split-precision MFMA, double-buffered B --------
// Also zeroes agg (for the next layer) after reading it.
__global__ __launch_bounds__(512, 2) void k_gru(
    float* __restrict__ h, __bf16* __restrict__ hb,
    float* __restrict__ agg,
    const __bf16* __restrict__ Wg,
    const float* __restrict__ bih, const float* __restrict__ bhh,
    int n_nodes)
{
    const int nb = blockIdx.x * 32;
    const int tid = threadIdx.x;
    __shared__ __bf16 sIn[4][32][HS];   // agg_hi, agg_lo, h_hi, h_lo (34.8 KB)

    // ---- stage + split inputs (1024 float4s, 2 per thread); zero agg ----
#pragma unroll
    for (int v = 0; v < 2; v++) {
        int idx = tid + 512 * v;
        int e = idx >> 5, c4 = (idx & 31) * 4;
        int n = nb + e;
        float4 av = {0.f, 0.f, 0.f, 0.f}, hv = {0.f, 0.f, 0.f, 0.f};
        if (n < n_nodes) {
            av = *(const float4*)(agg + (size_t)n * H + c4);
            hv = *(const float4*)(h + (size_t)n * H + c4);
            float4 z = {0.f, 0.f, 0.f, 0.f};
            *(float4*)(agg + (size_t)n * H + c4) = z;   // ready for next layer
        }
        bf16x4 ahi, alo, hhi, hlo;
        float af[4] = {av.x, av.y, av.z, av.w};
        float hf[4] = {hv.x, hv.y, hv.z, hv.w};
#pragma unroll
        for (int c = 0; c < 4; c++) {
            __bf16 ah = (__bf16)af[c]; ahi[c] = ah; alo[c] = (__bf16)(af[c] - (float)ah);
            __bf16 hh = (__bf16)hf[c]; hhi[c] = hh; hlo[c] = (__bf16)(hf[c] - (float)hh);
        }
        *(bf16x4*)&sIn[0][e][c4] = ahi;
        *(bf16x4*)&sIn[1][e][c4] = alo;
        *(bf16x4*)&sIn[2][e][c4] = hhi;
        *(bf16x4*)&sIn[3][e][c4] = hlo;
    }
    __syncthreads();

    const int lane = tid & 63, w = tid >> 6;     // w: 0..7
    const int r = lane & 15, quad = lane >> 4;
    const int jt = w;

    f32x4 acc[2][3][2];                  // [m][gate][mat]
#pragma unroll
    for (int m = 0; m < 2; m++)
#pragma unroll
        for (int g = 0; g < 3; g++)
#pragma unroll
            for (int mat = 0; mat < 2; mat++)
                acc[m][g][mat] = (f32x4){0.f, 0.f, 0.f, 0.f};

    bf16x8 B[2][12];
#pragma unroll
    for (int mat = 0; mat < 2; mat++)
#pragma unroll
    for (int g = 0; g < 3; g++)
#pragma unroll
    for (int sp = 0; sp < 2; sp++)
        B[0][mat * 6 + g * 2 + sp] = *(const bf16x8*)(Wg +
            ((((size_t)(mat * 2 + sp) * 4 + 0) * 24 + (g * 8 + jt)) * 64 + lane) * 8);

#pragma unroll
    for (int kc = 0; kc < 4; kc++) {
        const int cur = kc & 1, nxt = cur ^ 1;
        if (kc < 3) {
#pragma unroll
            for (int mat = 0; mat < 2; mat++)
#pragma unroll
            for (int g = 0; g < 3; g++)
#pragma unroll
            for (int sp = 0; sp < 2; sp++)
                B[nxt][mat * 6 + g * 2 + sp] = *(const bf16x8*)(Wg +
                    ((((size_t)(mat * 2 + sp) * 4 + (kc + 1)) * 24 + (g * 8 + jt)) * 64 + lane) * 8);
        }
        bf16x8 A[2][4];
#pragma unroll
        for (int m = 0; m < 2; m++)
#pragma unroll
            for (int s = 0; s < 4; s++)
                A[m][s] = *(const bf16x8*)&sIn[s][m * 16 + r][kc * 32 + quad * 8];
#pragma unroll
        for (int g = 0; g < 3; g++)
#pragma unroll
        for (int mat = 0; mat < 2; mat++) {
            bf16x8 bhi = B[cur][mat * 6 + g * 2 + 0];
            bf16x8 blo = B[cur][mat * 6 + g * 2 + 1];
            int s = mat * 2;
#pragma unroll
            for (int m = 0; m < 2; m++) {
                acc[m][g][mat] = __builtin_amdgcn_mfma_f32_16x16x32_bf16(
                    A[m][s], bhi, acc[m][g][mat], 0, 0, 0);
                acc[m][g][mat] = __builtin_amdgcn_mfma_f32_16x16x32_bf16(
                    A[m][s], blo, acc[m][g][mat], 0, 0, 0);
                acc[m][g][mat] = __builtin_amdgcn_mfma_f32_16x16x32_bf16(
                    A[m][s + 1], bhi, acc[m][g][mat], 0, 0, 0);
            }
        }
    }

    // ---- gate epilogue (register-only) ----
    const int jcol = jt * 16 + r;
    float br_ = bih[jcol], bz_ = bih[128 + jcol], bn_ = bih[256 + jcol];
    float cr = bhh[jcol], cz = bhh[128 + jcol], cn = bhh[256 + jcol];
#pragma unroll
    for (int m = 0; m < 2; m++)
#pragma unroll
    for (int g4 = 0; g4 < 4; g4++) {
        int n = nb + m * 16 + quad * 4 + g4;
        if (n < n_nodes) {
            float ir = acc[m][0][0][g4], hr = acc[m][0][1][g4];
            float iz = acc[m][1][0][g4], hz = acc[m][1][1][g4];
            float in_ = acc[m][2][0][g4], hn = acc[m][2][1][g4];
            float hold = h[(size_t)n * H + jcol];
            float rr = 1.f / (1.f + expf(-(ir + br_ + hr + cr)));
            float zz = 1.f / (1.f + expf(-(iz + bz_ + hz + cz)));
            float nv = tanhf(in_ + bn_ + rr * (hn + cn));
            float out = (1.f - zz) * nv + zz * hold;
            h[(size_t)n * H + jcol] = out;
            hb[(size_t)n * H + jcol] = (__bf16)out;
        }
    }
}

// ---------------- readout: out = relu(h@Wr1+br1) @ Wr2 + br2 ---------------
__global__ __launch_bounds__(128) void k_readout(
    const float* __restrict__ h, const float* __restrict__ Wr1,
    const float* __restrict__ br1, const float* __restrict__ Wr2,
    const float* __restrict__ br2, float* __restrict__ out, int n_out)
{
    const int n0 = blockIdx.x * 16;
    const int tid = threadIdx.x;     // 128
    __shared__ float sh[16][H];      // 8 KB
    __shared__ float sRed[2][16];
    {
#pragma unroll
        for (int v = 0; v < 4; v++) {
            int idx = tid + 128 * v;          // float4 id, 512 total
            int e = idx >> 5, q = (idx & 31) * 4;
            int n = n0 + e;
            if (n < n_out)
                *(float4*)&sh[e][q] = *(const float4*)(h + (size_t)n * H + q);
        }
    }
    __syncthreads();

    const int j = tid;
    float bb = br1[j];
    float acc[16];
#pragma unroll
    for (int e = 0; e < 16; e++) acc[e] = bb;
    for (int k = 0; k < H; k++) {
        float wv = Wr1[k * H + j];
#pragma unroll
        for (int e = 0; e < 16; e++) acc[e] += sh[e][k] * wv;
    }
    float w2 = Wr2[j];
    int lane = tid & 63, w = tid >> 6;
#pragma unroll
    for (int e = 0; e < 16; e++) {
        float val = fmaxf(acc[e], 0.f) * w2;
#pragma unroll
        for (int off = 32; off > 0; off >>= 1)
            val += __shfl_down(val, off, 64);
        if (lane == 0) sRed[w][e] = val;
    }
    __syncthreads();
    if (tid < 16 && n0 + tid < n_out)
        out[n0 + tid] = sRed[0][tid] + sRed[1][tid] + br2[0];
}

// ---------------------------------------------------------------------------
extern "C" void kernel_launch(void* const* d_in, const int* in_sizes, int n_in,
                              void* d_out, int out_size, void* d_ws, size_t ws_size,
                              hipStream_t stream)
{
    const float* x      = (const float*)d_in[0];
    const int*   eidx   = (const int*)d_in[1];
    const int*   etype  = (const int*)d_in[2];
    const float* Win    = (const float*)d_in[4];
    const float* bin    = (const float*)d_in[5];
    const float* W1     = (const float*)d_in[6];   // (3,2,256,128)
    const float* b1     = (const float*)d_in[7];   // (3,2,128)
    const float* W2     = (const float*)d_in[8];   // (3,2,128,128)
    const float* b2     = (const float*)d_in[9];   // (3,2,128)
    const float* Wih    = (const float*)d_in[10];  // (3,128,384)
    const float* bih    = (const float*)d_in[11];  // (3,384)
    const float* Whh    = (const float*)d_in[12];  // (3,128,384)
    const float* bhh    = (const float*)d_in[13];  // (3,384)
    const float* Wr1    = (const float*)d_in[14];
    const float* br1    = (const float*)d_in[15];
    const float* Wr2    = (const float*)d_in[16];
    const float* br2    = (const float*)d_in[17];

    const int n_nodes = in_sizes[0] / FEAT;
    const int n_edges = in_sizes[1] / 2;
    const int L = 3;
    const size_t nh = (size_t)n_nodes * H;

    const int* src = eidx;
    const int* dst = eidx + n_edges;

    // workspace carve-up
    float*  h    = (float*)d_ws;                    // 25.6 MB
    float*  agg  = h + nh;                          // 25.6 MB
    __bf16* hb   = (__bf16*)(agg + nh);             // 12.8 MB
    __bf16* Wsw  = hb + nh;                         // 6*12*4096 bf16
    __bf16* Wg   = Wsw + 6 * 12 * 4096;             // 3*WG_PER_LAYER bf16
    int* bucket  = (int*)(Wg + 3 * WG_PER_LAYER);   // n_edges
    int* cnt     = bucket + n_edges;                // 2*nn (also k_place cursors)
    int* offs    = cnt + 2 * n_nodes;               // 2*nn + 1
    int* bsum    = offs + 2 * n_nodes + 1;          // scan block sums

    const int nscan = 2 * n_nodes;
    const int nb = (nscan + 1023) / 1024;

    hipMemsetAsync(cnt, 0, (size_t)nscan * sizeof(int), stream);

    k_wconv<<<(6 * 12 * 4096 + 255) / 256, 256, 0, stream>>>(W1, W2, Wsw);
    k_wgconv<<<(3 * WG_PER_LAYER + 255) / 256, 256, 0, stream>>>(Wih, Whh, Wg);
    k_input<<<((int)nh + 255) / 256, 256, 0, stream>>>(x, Win, bin, h, hb, n_nodes);

    const int eb = (n_edges + 255) / 256;
    k_hist <<<eb, 256, 0, stream>>>(etype, dst, cnt, n_edges, n_nodes);
    k_scan1<<<nb, 1024, 0, stream>>>(cnt, bsum, nscan);
    k_scan2<<<1, 128, 0, stream>>>(bsum, offs, nb, nscan);
    k_scan3<<<nb, 1024, 0, stream>>>(cnt, bsum, offs, nscan);
    k_place<<<eb, 256, 0, stream>>>(etype, dst, offs, cnt, bucket, n_edges, n_nodes);

    // agg zeroed once here; k_gru re-zeroes it for the following layer
    hipMemsetAsync(agg, 0, nh * sizeof(float), stream);

    const dim3 mgrid((n_edges + TE2 - 1) / TE2, 2);
    for (int l = 0; l < L; l++) {
        k_msg<<<mgrid, 512, 0, stream>>>(
            hb, bucket, offs, src, dst,
            Wsw + (size_t)l * 2 * 12 * 4096,
            b1 + (size_t)l * 2 * H, b2 + (size_t)l * 2 * H,
            agg, n_edges, n_nodes);
        k_gru<<<(n_nodes + 31) / 32, 512, 0, stream>>>(
            h, hb, agg,
            Wg + (size_t)l * WG_PER_LAYER,
            bih + (size_t)l * 384, bhh + (size_t)l * 384,
            n_nodes);
    }

    k_readout<<<(out_size + 15) / 16, 128, 0, stream>>>(
        h, Wr1, br1, Wr2, br2, (float*)d_out, out_size);
}